// Round 4
// baseline (260.179 us; speedup 1.0000x reference)
//
#include <hip/hip_runtime.h>
#include <hip/hip_bf16.h>

// AttentionHead: B=4, T=2048, C=1024, hs=64. All fp32 in/out.
// Fused single-kernel: prep -> qkv -> attn -> combine, software grid barriers.
// Round 4: 512 blocks = 2 blocks/CU (TLP for latency hiding), 64KB LDS union.
#define D_MODEL 1024
#define HS 64
#define T_LEN 2048
#define JCH 256          // j-chunk width per attention item
#define NCH 8            // max chunks per row = T_LEN/JCH
#define NBLK 512         // grid size; 2 blocks/CU, all co-resident
#define NBLK_LOG 9

typedef __attribute__((ext_vector_type(8))) short bf16x8;   // MFMA A/B frag
typedef __attribute__((ext_vector_type(4))) float f32x4;    // MFMA C/D frag

// split 8 floats into hi/lo bf16 (truncation split: residual exact)
__device__ inline void split8(const float* v, int4& hi, int4& lo) {
    union { unsigned short u[8]; int4 v4; } uh, ul;
    #pragma unroll
    for (int i = 0; i < 8; ++i) {
        const unsigned int b = __float_as_uint(v[i]);
        const unsigned short h = (unsigned short)(b >> 16);
        const float r = v[i] - __uint_as_float((unsigned int)h << 16);
        uh.u[i] = h;
        ul.u[i] = (unsigned short)(__float_as_uint(r) >> 16);
    }
    hi = uh.v4; lo = ul.v4;
}

// fp32 -> bf16 round-to-nearest-even (finite inputs only here)
__device__ inline unsigned short f2bf_rne(float f) {
    const unsigned int b = __float_as_uint(f);
    return (unsigned short)((b + 0x7FFFu + ((b >> 16) & 1u)) >> 16);
}
__device__ inline float bf2f(unsigned short h) {
    return __uint_as_float((unsigned int)h << 16);
}

// async 16B global -> LDS (direct-to-shared DMA). LDS dest is wave-uniform
// base; HW writes ldsbase + lane*16. gptr is per-lane.
__device__ inline void async_copy16(const short* g, short* l) {
    __builtin_amdgcn_global_load_lds(
        (const __attribute__((address_space(1))) void*)g,
        (__attribute__((address_space(3))) void*)l, 16, 0, 0);
}

// stage the full B panel (12 n-tiles x 64 k) for 64-wide chunk `ch` into LDS.
__device__ inline void stage_B(const short* __restrict__ wh,
                               const short* __restrict__ wl,
                               short* Bdst, int ch, int wave, int lane) {
    #pragma unroll
    for (int ii = 0; ii < 12; ++ii) {
        const int g   = wave * 12 + ii;       // 0..47
        const int nt  = g >> 2;
        const int kcl = (g >> 1) & 1;
        const int p   = g & 1;
        const short* src = (p ? wl : wh)
                         + ((size_t)(nt * 32 + ch * 2 + kcl)) * 512;
        async_copy16(src + lane * 8, Bdst + g * 512);
    }
}

// ---------------------------------------------------------------------------
// Cheap software grid barrier: tid0-only {release fence, relaxed add,
// relaxed spin, acquire fence}. g_tick advances exactly NBLK per barrier ->
// monotone target math is replay-safe without reset.
// ---------------------------------------------------------------------------
__device__ unsigned int g_tick;
__device__ unsigned int g_work;   // attn work queue; +1024 per launch exactly

__device__ __forceinline__ void grid_barrier() {
    __syncthreads();   // all waves' stores drained (compiler waitcnt)
    if (threadIdx.x == 0) {
        __builtin_amdgcn_fence(__ATOMIC_RELEASE, "agent");   // 1x L2 writeback
        const unsigned int t = __hip_atomic_fetch_add(
            &g_tick, 1u, __ATOMIC_RELAXED, __HIP_MEMORY_SCOPE_AGENT);
        const unsigned int target = ((t >> NBLK_LOG) + 1u) << NBLK_LOG;
        while (__hip_atomic_load(&g_tick, __ATOMIC_RELAXED,
                                 __HIP_MEMORY_SCOPE_AGENT) < target) {
            __builtin_amdgcn_s_sleep(4);
        }
        __builtin_amdgcn_fence(__ATOMIC_ACQUIRE, "agent");   // 1x L1/L2 inv
    }
    __syncthreads();
}

// ---------------------------------------------------------------------------
// The fused kernel. LDS union = 64KB (2 blocks/CU):
//   prep : float tile[64][69]                     (17.6 KB)
//   qkv  : A[2][2048] shorts @0, B[48*512] @8KB   (56 KB)
//   attn : KV[2][12288] shorts @0, P @48KB        (58.4 KB)
// ---------------------------------------------------------------------------
__global__ __launch_bounds__(256, 2) void fused_kernel(
    const float* __restrict__ x,
    const float* __restrict__ Wq, const float* __restrict__ Wk,
    const float* __restrict__ Wv,
    const float* __restrict__ bq, const float* __restrict__ bk,
    const int* __restrict__ maskp,
    short* __restrict__ wh, short* __restrict__ wl,
    short* __restrict__ qfh, short* __restrict__ qfl,
    short* __restrict__ kfh, short* __restrict__ kfl, short* __restrict__ vf,
    float* __restrict__ part_O, float* __restrict__ part_ml,
    float* __restrict__ out, int BT)
{
    __shared__ __align__(16) char smem[65536];
    __shared__ int s_item;
    const int tid = threadIdx.x;
    const int bx  = blockIdx.x;

    // ================= Phase 0: W prep (blocks 0..47) =================
    if (bx < 48) {
        float (*tile)[69] = (float (*)[69])smem;
        const int kb = bx & 15;
        const int m  = bx >> 4;
        const float* W = (m == 0) ? Wq : (m == 1) ? Wk : Wv;
        #pragma unroll
        for (int it = 0; it < 4; ++it) {
            const int idx = tid + 256 * it;
            const int kr = idx >> 4, c4 = idx & 15;
            *(float4*)&tile[kr][4 * c4] =
                *(const float4*)(W + (size_t)(kb * 64 + kr) * HS + 4 * c4);
        }
        __syncthreads();
        #pragma unroll
        for (int i = 0; i < 2; ++i) {
            const int s    = tid + 256 * i;    // 0..511
            const int ntl  = s >> 7;
            const int kcl  = (s >> 6) & 1;
            const int lane = s & 63;
            const int n    = ntl * 16 + (lane & 15);
            const int krel = kcl * 32 + (lane >> 4) * 8;
            float v[8];
            #pragma unroll
            for (int e = 0; e < 8; ++e) v[e] = tile[krel + e][n];
            int4 hi, lo;
            split8(v, hi, lo);
            const size_t off =
                ((size_t)((m * 4 + ntl) * 32 + kb * 2 + kcl) * 64 + lane) * 8;
            *(int4*)(wh + off) = hi;
            *(int4*)(wl + off) = lo;
        }
    }
    grid_barrier();

    // ================= Phase 1: fused QKV projection (16-row tiles) ======
    for (int g = bx; g < (BT >> 4); g += NBLK) {
        short* const A0 = (short*)smem;            // 2 x 2048 shorts (dbuf)
        short* const Bb = (short*)(smem + 8192);   // 48 frags x 512 shorts
        const int r0    = g * 16;
        const int wave  = tid >> 6;
        const int lane  = tid & 63;
        const int nt0   = wave * 3;
        const bool cvt  = (tid < 128);             // waves 0-1 convert A
        const int kcl_l = (tid >> 6) & 1;

        const float* xrow = x + (size_t)(r0 + (lane & 15)) * D_MODEL
                              + kcl_l * 32 + (lane >> 4) * 8;

        f32x4 acc[3];
        #pragma unroll
        for (int j = 0; j < 3; ++j) acc[j] = (f32x4)(0.f);

        // prologue: convert A chunk 0 into buffer 0
        if (cvt) {
            float v[8];
            *(float4*)&v[0] = *(const float4*)(xrow);
            *(float4*)&v[4] = *(const float4*)(xrow + 4);
            int4 hi, lo;
            split8(v, hi, lo);
            *(int4*)&A0[(kcl_l * 2 + 0) * 512 + lane * 8] = hi;
            *(int4*)&A0[(kcl_l * 2 + 1) * 512 + lane * 8] = lo;
        }

        int cur = 0;
        for (int t = 0; t < 16; ++t) {
            stage_B(wh, wl, Bb, t, wave, lane);    // single-buffered B
            float v[8];
            const bool pf = (t < 15) && cvt;
            if (pf) {
                *(float4*)&v[0] = *(const float4*)(xrow + (t + 1) * 64);
                *(float4*)&v[4] = *(const float4*)(xrow + (t + 1) * 64 + 4);
            }
            // one combined wait: B[t] stage + x[t+1] regs + A[t] LDS writes
            __syncthreads();

            const short* Ac = A0 + cur * 2048;
            #pragma unroll
            for (int kcl = 0; kcl < 2; ++kcl) {
                const bf16x8 afh = *(const bf16x8*)&Ac[(kcl * 2 + 0) * 512 + lane * 8];
                const bf16x8 afl = *(const bf16x8*)&Ac[(kcl * 2 + 1) * 512 + lane * 8];
                #pragma unroll
                for (int j = 0; j < 3; ++j) {
                    const int gb = (nt0 + j) * 4 + kcl * 2;
                    const bf16x8 bh = *(const bf16x8*)&Bb[(gb + 0) * 512 + lane * 8];
                    const bf16x8 bl = *(const bf16x8*)&Bb[(gb + 1) * 512 + lane * 8];
                    acc[j] = __builtin_amdgcn_mfma_f32_16x16x32_bf16(afh, bh, acc[j], 0, 0, 0);
                    acc[j] = __builtin_amdgcn_mfma_f32_16x16x32_bf16(afh, bl, acc[j], 0, 0, 0);
                    acc[j] = __builtin_amdgcn_mfma_f32_16x16x32_bf16(afl, bh, acc[j], 0, 0, 0);
                }
            }
            if (pf) {
                int4 hi, lo;
                split8(v, hi, lo);
                short* An = A0 + (cur ^ 1) * 2048;
                *(int4*)&An[(kcl_l * 2 + 0) * 512 + lane * 8] = hi;
                *(int4*)&An[(kcl_l * 2 + 1) * 512 + lane * 8] = lo;
            }
            __syncthreads();   // A[t+1] visible; all B readers done
            cur ^= 1;
        }

        // epilogue: C/D layout col=lane&15, row=(lane>>4)*4+reg
        const int quad = lane >> 4;
        const int l15  = lane & 15;
        const int rowb = r0 + quad * 4;
        #pragma unroll
        for (int j = 0; j < 3; ++j) {
            const f32x4 a = acc[j];
            const int c = (nt0 + j) * 16 + l15;    // 0..191
            if (c < 128) {
                const int cc    = (c < 64) ? c : (c - 64);
                const float bias = (c < 64) ? bq[cc] : bk[cc];
                short* dsth = (c < 64) ? qfh : kfh;
                short* dstl = (c < 64) ? qfl : kfl;
                const int tile16 = rowb >> 4;
                const int kc2   = cc >> 5;
                const int quadd = (cc & 31) >> 3;
                const int e     = cc & 7;
                #pragma unroll
                for (int r = 0; r < 4; ++r) {
                    const float val = a[r] + bias;
                    const unsigned int b = __float_as_uint(val);
                    const unsigned short h = (unsigned short)(b >> 16);
                    const float res = val - __uint_as_float((unsigned int)h << 16);
                    const unsigned short l16 = (unsigned short)(__float_as_uint(res) >> 16);
                    const int laned = ((rowb + r) & 15) | (quadd << 4);
                    const size_t off = ((size_t)((tile16 * 2 + kc2) * 64 + laned)) * 8 + e;
                    dsth[off] = (short)h;
                    dstl[off] = (short)l16;
                }
            } else {
                const int cv    = c - 128;
                const int vb    = rowb >> 6;
                const int jc2   = (rowb & 63) >> 5;
                const int quadd = (rowb & 31) >> 3;
                const int gg    = jc2 * 4 + (cv >> 4);
                const int laned = (cv & 15) | (quadd << 4);
                const size_t base = ((size_t)((vb * 8 + gg) * 64 + laned)) * 8 + (rowb & 7);
                short4 pk;
                pk.x = (short)f2bf_rne(a[0]);
                pk.y = (short)f2bf_rne(a[1]);
                pk.z = (short)f2bf_rne(a[2]);
                pk.w = (short)f2bf_rne(a[3]);
                *(short4*)(vf + base) = pk;
            }
        }
    }
    grid_barrier();

    // ================= Phase 2: flash attention (dbuf + work queue) ======
    {
        const int ntile  = BT >> 6;           // 128
        const int nitems = ntile * NCH;       // 1024
        const int pops   = nitems / NBLK;     // 2 per block (exact)
        short* const KV0 = (short*)smem;      // 2 x 12288 shorts (24KB each)
        short* const Pm  = (short*)(smem + 49152);   // 4 x 1152 shorts

        const int w    = tid >> 6;
        const int lane = tid & 63;
        const int quad = lane >> 4;
        const int l15  = lane & 15;
        const int mask = (*maskp != 0);

        for (int pop = 0; pop < pops; ++pop) {
            if (tid == 0) {
                s_item = (int)(__hip_atomic_fetch_add(
                    &g_work, 1u, __ATOMIC_RELAXED, __HIP_MEMORY_SCOPE_AGENT)
                    & (unsigned)(nitems - 1));
            }
            __syncthreads();   // broadcast item + protect LDS from prev item
            const int u      = s_item;
            const int chunk  = u >> 7;          // 0..7 (big chunks first)
            const int batch  = (u >> 5) & 3;
            const int tilein = 31 - (u & 31);   // expensive tiles first
            const int r0 = (batch * 32 + tilein) * 64;
            const int tb = batch;
            const int t0 = tilein * 64;
            const int n_max = mask ? (t0 + 64) : T_LEN;
            const int j0 = chunk * JCH;
            if (j0 >= n_max) continue;          // inactive item (still popped)
            const int hi_j = min(j0 + JCH, n_max);
            const int njt = (hi_j - j0 + 63) >> 6;

            const int rw0  = t0 + 16 * w;
            const int rowa = r0 + 16 * w + quad * 4;

            bf16x8 qh[2], ql[2];
            {
                const size_t qt = (size_t)(r0 >> 4) + w;
                #pragma unroll
                for (int kc = 0; kc < 2; ++kc) {
                    qh[kc] = *(const bf16x8*)&qfh[((qt * 2 + kc) * 64 + lane) * 8];
                    ql[kc] = *(const bf16x8*)&qfl[((qt * 2 + kc) * 64 + lane) * 8];
                }
            }

            f32x4 oacc[4];
            #pragma unroll
            for (int nt = 0; nt < 4; ++nt) oacc[nt] = (f32x4)(0.f);
            float m_r[4] = {-INFINITY, -INFINITY, -INFINITY, -INFINITY};
            float l_r[4] = {0.f, 0.f, 0.f, 0.f};

            // prologue: stage jt=0 into buffer 0
            {
                const size_t kt0 = (size_t)(tb * 128) + (j0 >> 4);
                const size_t vb  = (size_t)(tb * 32) + (j0 >> 6);
                short* Kb = KV0;
                #pragma unroll
                for (int ii = 0; ii < 6; ++ii) {
                    const int g = w * 6 + ii;
                    if (g < 8) {
                        const short* src = kfh + ((kt0 + (g >> 1)) * 2 + (g & 1)) * 512;
                        async_copy16(src + lane * 8, Kb + g * 512);
                    } else if (g < 16) {
                        const int gg = g - 8;
                        const short* src = kfl + ((kt0 + (gg >> 1)) * 2 + (gg & 1)) * 512;
                        async_copy16(src + lane * 8, Kb + 4096 + gg * 512);
                    } else {
                        const int gg = g - 16;
                        const short* src = vf + (vb * 8 + gg) * 512;
                        async_copy16(src + lane * 8, Kb + 8192 + gg * 512);
                    }
                }
            }

            int cur = 0;
            for (int jt = 0; jt < njt; ++jt) {
                const int jbase = j0 + jt * 64;
                __syncthreads();   // buf[cur] staged (drains own-wave queue)
                if (jt + 1 < njt) {
                    const int jb2 = j0 + (jt + 1) * 64;
                    const size_t kt0 = (size_t)(tb * 128) + (jb2 >> 4);
                    const size_t vb  = (size_t)(tb * 32) + (jb2 >> 6);
                    short* Kb = KV0 + (cur ^ 1) * 12288;
                    #pragma unroll
                    for (int ii = 0; ii < 6; ++ii) {
                        const int g = w * 6 + ii;
                        if (g < 8) {
                            const short* src = kfh + ((kt0 + (g >> 1)) * 2 + (g & 1)) * 512;
                            async_copy16(src + lane * 8, Kb + g * 512);
                        } else if (g < 16) {
                            const int gg = g - 8;
                            const short* src = kfl + ((kt0 + (gg >> 1)) * 2 + (gg & 1)) * 512;
                            async_copy16(src + lane * 8, Kb + 4096 + gg * 512);
                        } else {
                            const int gg = g - 16;
                            const short* src = vf + (vb * 8 + gg) * 512;
                            async_copy16(src + lane * 8, Kb + 8192 + gg * 512);
                        }
                    }
                }

                const short* Kh = KV0 + cur * 12288;
                const short* Kl = Kh + 4096;
                const short* Vt = Kh + 8192;
                const bool active = (!mask) || (jbase <= rw0 + 15);
                if (active) {
                    f32x4 sacc[4];
                    #pragma unroll
                    for (int jsub = 0; jsub < 4; ++jsub) {
                        f32x4 s = (f32x4)(0.f);
                        #pragma unroll
                        for (int kc = 0; kc < 2; ++kc) {
                            const bf16x8 kh = *(const bf16x8*)&Kh[((jsub * 2 + kc) * 64 + lane) * 8];
                            const bf16x8 kl = *(const bf16x8*)&Kl[((jsub * 2 + kc) * 64 + lane) * 8];
                            s = __builtin_amdgcn_mfma_f32_16x16x32_bf16(qh[kc], kh, s, 0, 0, 0);
                            s = __builtin_amdgcn_mfma_f32_16x16x32_bf16(qh[kc], kl, s, 0, 0, 0);
                            s = __builtin_amdgcn_mfma_f32_16x16x32_bf16(ql[kc], kh, s, 0, 0, 0);
                        }
                        sacc[jsub] = s;
                    }
                    float sval[4][4], rmax[4];
                    #pragma unroll
                    for (int r = 0; r < 4; ++r) rmax[r] = -INFINITY;
                    #pragma unroll
                    for (int jsub = 0; jsub < 4; ++jsub) {
                        const int jg = jbase + jsub * 16 + l15;
                        #pragma unroll
                        for (int r = 0; r < 4; ++r) {
                            const int tg = rw0 + quad * 4 + r;
                            const float vv = (mask && (jg > tg)) ? -INFINITY : 8.0f * sacc[jsub][r];
                            sval[jsub][r] = vv;
                            rmax[r] = fmaxf(rmax[r], vv);
                        }
                    }
                    #pragma unroll
                    for (int d = 1; d < 16; d <<= 1)
                        #pragma unroll
                        for (int r = 0; r < 4; ++r)
                            rmax[r] = fmaxf(rmax[r], __shfl_xor(rmax[r], d));
                    float alpha[4], msafe[4];
                    #pragma unroll
                    for (int r = 0; r < 4; ++r) {
                        const float mn = fmaxf(m_r[r], rmax[r]);
                        msafe[r] = (mn == -INFINITY) ? 0.f : mn;
                        alpha[r] = __expf(m_r[r] - msafe[r]);
                        m_r[r] = mn;
                    }
                    short* Pw = Pm + w * 1152;
                    float rsum[4] = {0.f, 0.f, 0.f, 0.f};
                    #pragma unroll
                    for (int jsub = 0; jsub < 4; ++jsub) {
                        #pragma unroll
                        for (int r = 0; r < 4; ++r) {
                            const float e = __expf(sval[jsub][r] - msafe[r]);
                            const unsigned short eb = f2bf_rne(e);
                            Pw[(quad * 4 + r) * 72 + jsub * 16 + l15] = (short)eb;
                            rsum[r] += bf2f(eb);
                        }
                    }
                    #pragma unroll
                    for (int d = 1; d < 16; d <<= 1)
                        #pragma unroll
                        for (int r = 0; r < 4; ++r)
                            rsum[r] += __shfl_xor(rsum[r], d);
                    #pragma unroll
                    for (int r = 0; r < 4; ++r)
                        l_r[r] = l_r[r] * alpha[r] + rsum[r];
                    #pragma unroll
                    for (int nt = 0; nt < 4; ++nt)
                        #pragma unroll
                        for (int r = 0; r < 4; ++r)
                            oacc[nt][r] *= alpha[r];
                    bf16x8 pf[2];
                    #pragma unroll
                    for (int jc = 0; jc < 2; ++jc)
                        pf[jc] = *(const bf16x8*)&Pw[l15 * 72 + jc * 32 + quad * 8];
                    #pragma unroll
                    for (int nt = 0; nt < 4; ++nt) {
                        #pragma unroll
                        for (int jc = 0; jc < 2; ++jc) {
                            const bf16x8 vfr = *(const bf16x8*)&Vt[((jc * 4 + nt) * 64 + lane) * 8];
                            oacc[nt] = __builtin_amdgcn_mfma_f32_16x16x32_bf16(pf[jc], vfr, oacc[nt], 0, 0, 0);
                        }
                    }
                }
                cur ^= 1;
            }

            #pragma unroll
            for (int nt = 0; nt < 4; ++nt)
                #pragma unroll
                for (int r = 0; r < 4; ++r)
                    part_O[((size_t)(rowa + r) * NCH + chunk) * HS + nt * 16 + l15] = oacc[nt][r];
            if (l15 == 0) {
                #pragma unroll
                for (int r = 0; r < 4; ++r) {
                    float2 ml;
                    ml.x = m_r[r];
                    ml.y = l_r[r];
                    *(float2*)(part_ml + ((size_t)(rowa + r) * NCH + chunk) * 2) = ml;
                }
            }
        }
    }
    grid_barrier();

    // ================= Phase 3: combine (1 item/thread exactly) ==========
    {
        const int mask = (*maskp != 0);
        for (int f = bx * 256 + tid; f < BT * 16; f += NBLK * 256) {
            const int row = f >> 4;
            const int d4 = (f & 15) * 4;
            const int t = row & (T_LEN - 1);
            const int n = mask ? (t + 1) : T_LEN;
            const int nc = (n + JCH - 1) / JCH;

            const float2* mlp = (const float2*)(part_ml + (size_t)row * NCH * 2);
            float M = -INFINITY;
            for (int c = 0; c < nc; ++c) M = fmaxf(M, mlp[c].x);
            float L = 0.f;
            float Ox = 0.f, Oy = 0.f, Oz = 0.f, Ow = 0.f;
            for (int c = 0; c < nc; ++c) {
                const float2 ml = mlp[c];
                const float wgt = __expf(ml.x - M);
                L += ml.y * wgt;
                const float4 p = *(const float4*)(part_O + ((size_t)row * NCH + c) * HS + d4);
                Ox = fmaf(p.x, wgt, Ox);
                Oy = fmaf(p.y, wgt, Oy);
                Oz = fmaf(p.z, wgt, Oz);
                Ow = fmaf(p.w, wgt, Ow);
            }
            float4 res;
            res.x = Ox / L;
            res.y = Oy / L;
            res.z = Oz / L;
            res.w = Ow / L;
            *(float4*)(out + (size_t)row * HS + d4) = res;
        }
    }
}

// ---------------------------------------------------------------------------
extern "C" void kernel_launch(void* const* d_in, const int* in_sizes, int n_in,
                              void* d_out, int out_size, void* d_ws, size_t ws_size,
                              hipStream_t stream) {
    const float* x  = (const float*)d_in[0];
    const float* Wq = (const float*)d_in[1];
    const float* bq = (const float*)d_in[2];
    const float* Wk = (const float*)d_in[3];
    const float* bk = (const float*)d_in[4];
    const float* Wv = (const float*)d_in[5];
    const int* maskp = (const int*)d_in[6];

    const int BT = in_sizes[0] / D_MODEL;   // 8192

    // ws layout: floats pO [BT*NCH*64], pml [BT*NCH*2]; shorts wh,wl
    // [192*1024], qfh,qfl,kfh,kfl,vf [BT*64].
    float* pO  = (float*)d_ws;
    float* pml = pO + (size_t)BT * NCH * HS;
    short* wh  = (short*)(pml + (size_t)BT * NCH * 2);
    short* wl  = wh + (size_t)192 * D_MODEL;
    short* qfh = wl + (size_t)192 * D_MODEL;
    short* qfl = qfh + (size_t)BT * HS;
    short* kfh = qfl + (size_t)BT * HS;
    short* kfl = kfh + (size_t)BT * HS;
    short* vf  = kfl + (size_t)BT * HS;

    fused_kernel<<<NBLK, 256, 0, stream>>>(
        x, Wq, Wk, Wv, bq, bk, maskp,
        wh, wl, qfh, qfl, kfh, kfl, vf,
        pO, pml, (float*)d_out, BT);
}

// Round 5
// 147.731 us; speedup vs baseline: 1.7612x; 1.7612x over previous
//
#include <hip/hip_runtime.h>
#include <hip/hip_bf16.h>

// AttentionHead: B=4, T=2048, C=1024, hs=64. All fp32 in/out.
// Round 5: back to multi-kernel (fused persistent approach measured 141-215us
// vs 138us for the pipeline). qkv rebuilt with counted-vmcnt pipelining
// (raw s_barrier, loads in flight across barriers, never vmcnt(0) mid-loop).
#define D_MODEL 1024
#define HS 64
#define T_LEN 2048
#define JCH 256          // j-chunk width per attention block
#define NCH 8            // max chunks per row = T_LEN/JCH

typedef __attribute__((ext_vector_type(8))) short bf16x8;   // MFMA A/B frag
typedef __attribute__((ext_vector_type(4))) float f32x4;    // MFMA C/D frag

// split 8 floats into hi/lo bf16 (truncation split: residual exact)
__device__ inline void split8(const float* v, int4& hi, int4& lo) {
    union { unsigned short u[8]; int4 v4; } uh, ul;
    #pragma unroll
    for (int i = 0; i < 8; ++i) {
        const unsigned int b = __float_as_uint(v[i]);
        const unsigned short h = (unsigned short)(b >> 16);
        const float r = v[i] - __uint_as_float((unsigned int)h << 16);
        uh.u[i] = h;
        ul.u[i] = (unsigned short)(__float_as_uint(r) >> 16);
    }
    hi = uh.v4; lo = ul.v4;
}

// fp32 -> bf16 round-to-nearest-even (finite inputs only here)
__device__ inline unsigned short f2bf_rne(float f) {
    const unsigned int b = __float_as_uint(f);
    return (unsigned short)((b + 0x7FFFu + ((b >> 16) & 1u)) >> 16);
}
__device__ inline float bf2f(unsigned short h) {
    return __uint_as_float((unsigned int)h << 16);
}

// async 16B global -> LDS (direct-to-shared DMA). LDS dest is wave-uniform
// base; HW writes ldsbase + lane*16. gptr is per-lane.
__device__ inline void async_copy16(const short* g, short* l) {
    __builtin_amdgcn_global_load_lds(
        (const __attribute__((address_space(1))) void*)g,
        (__attribute__((address_space(3))) void*)l, 16, 0, 0);
}

// ---------------------------------------------------------------------------
// Kernel 0: prep — W ONLY. Grid: 48 blocks = 3 matrices x 16 k-blocks.
// Output wh/wl layout: ((g_nt*32 + kc)*64 + lane)*8, g_nt = m*4+ntl in 0..11.
// ---------------------------------------------------------------------------
__global__ __launch_bounds__(256) void prep_kernel(
    const float* __restrict__ Wq, const float* __restrict__ Wk,
    const float* __restrict__ Wv,
    short* __restrict__ wh, short* __restrict__ wl)
{
    __shared__ float tile[64][69];
    const int tid = threadIdx.x;
    const int wb  = blockIdx.x;
    const int kb  = wb & 15;           // k-block 0..15
    const int m   = wb >> 4;           // matrix 0..2
    const float* W = (m == 0) ? Wq : (m == 1) ? Wk : Wv;
    #pragma unroll
    for (int it = 0; it < 4; ++it) {
        const int idx = tid + 256 * it;
        const int kr = idx >> 4, c4 = idx & 15;
        *(float4*)&tile[kr][4 * c4] =
            *(const float4*)(W + (size_t)(kb * 64 + kr) * HS + 4 * c4);
    }
    __syncthreads();
    #pragma unroll
    for (int i = 0; i < 2; ++i) {
        const int s    = tid + 256 * i;    // 0..511
        const int ntl  = s >> 7;
        const int kcl  = (s >> 6) & 1;
        const int lane = s & 63;
        const int n    = ntl * 16 + (lane & 15);
        const int krel = kcl * 32 + (lane >> 4) * 8;
        float v[8];
        #pragma unroll
        for (int e = 0; e < 8; ++e) v[e] = tile[krel + e][n];
        int4 hi, lo;
        split8(v, hi, lo);
        const size_t off =
            ((size_t)((m * 4 + ntl) * 32 + kb * 2 + kcl) * 64 + lane) * 8;
        *(int4*)(wh + off) = hi;
        *(int4*)(wl + off) = lo;
    }
}

// stage the full B panel (12 n-tiles x 64 k) for 64-wide chunk `ch` into LDS.
// Wave-SELF-CONTAINED: wave w stages frags g=12w..12w+11 == exactly the frags
// it consumes (nt0=3w) -> B needs no cross-wave sync, only per-wave vmcnt.
__device__ inline void stage_B(const short* __restrict__ wh,
                               const short* __restrict__ wl,
                               short* Bdst, int ch, int wave, int lane) {
    #pragma unroll
    for (int ii = 0; ii < 12; ++ii) {
        const int g   = wave * 12 + ii;       // 0..47
        const int nt  = g >> 2;
        const int kcl = (g >> 1) & 1;
        const int p   = g & 1;
        const short* src = (p ? wl : wh)
                         + ((size_t)(nt * 32 + ch * 2 + kcl)) * 512;
        async_copy16(src + lane * 8, Bdst + g * 512);
    }
}

#define WAITVM(N) asm volatile("s_waitcnt vmcnt(" #N ")" ::: "memory")
#define WAITLGKM0 asm volatile("s_waitcnt lgkmcnt(0)" ::: "memory")

// ---------------------------------------------------------------------------
// Kernel 1: QKV projection, counted-vmcnt pipeline.
// Grid: BT/64 = 128 blocks x 256 threads. 64-row tiles, 192 output cols.
// LDS: A dbuf 2x16KB @0, B dbuf 2x48KB @32KB = 128KB (1 block/CU).
// Per chunk (64 k): issue x(t+1)->regs then B(t+1)->LDS^1 (stay in flight);
// s_waitcnt vmcnt(16) ensures only B(t) complete; MFMA; convert+ds_write
// A(t+1); lgkmcnt(0); raw s_barrier (A handoff). Never vmcnt(0) mid-loop.
// ---------------------------------------------------------------------------
__global__ __launch_bounds__(256) void qkv_kernel(
    const float* __restrict__ x,
    const short* __restrict__ wh, const short* __restrict__ wl,
    const float* __restrict__ bq, const float* __restrict__ bk,
    short* __restrict__ qfh, short* __restrict__ qfl,
    short* __restrict__ kfh, short* __restrict__ kfl, short* __restrict__ vf)
{
    __shared__ __align__(16) short A_lds[2][16 * 512];   // 2 x 16KB
    __shared__ __align__(16) short B_lds[2][48 * 512];   // 2 x 48KB

    const int tid   = threadIdx.x;
    const int r0    = blockIdx.x * 64;
    const int wave  = tid >> 6;
    const int lane  = tid & 63;
    const int nt0   = wave * 3;

    // A-conversion assignment: thread handles frag-pair fp = tid>>5 (0..7)
    // = (mt*2 + kcl), lanes l1 = tid&31 and l2 = l1+32 (same row, k+16).
    const int fp   = tid >> 5;
    const int l1   = tid & 31;
    const int mt_c = fp >> 1;
    const int kcl_c = fp & 1;
    const float* xp = x + (size_t)(r0 + mt_c * 16 + (l1 & 15)) * D_MODEL
                        + kcl_c * 32 + (l1 >> 4) * 8;

    f32x4 acc[4][3];
    #pragma unroll
    for (int mt = 0; mt < 4; ++mt)
        #pragma unroll
        for (int j = 0; j < 3; ++j) acc[mt][j] = (f32x4)(0.f);

    // ---- prologue: x(0) -> regs, B(0) -> buf0, A(0) -> buf0
    {
        float v1[8], v2[8];
        *(float4*)&v1[0] = *(const float4*)(xp);
        *(float4*)&v1[4] = *(const float4*)(xp + 4);
        *(float4*)&v2[0] = *(const float4*)(xp + 16);
        *(float4*)&v2[4] = *(const float4*)(xp + 20);
        stage_B(wh, wl, &B_lds[0][0], 0, wave, lane);
        int4 hi, lo;
        split8(v1, hi, lo);   // compiler waits vmcnt(12): only B(0) in flight
        *(int4*)&A_lds[0][(fp * 2 + 0) * 512 + l1 * 8] = hi;
        *(int4*)&A_lds[0][(fp * 2 + 1) * 512 + l1 * 8] = lo;
        split8(v2, hi, lo);
        *(int4*)&A_lds[0][(fp * 2 + 0) * 512 + (l1 + 32) * 8] = hi;
        *(int4*)&A_lds[0][(fp * 2 + 1) * 512 + (l1 + 32) * 8] = lo;
        WAITLGKM0;
        __builtin_amdgcn_s_barrier();
        __builtin_amdgcn_sched_barrier(0);
    }

    int cur = 0;
    for (int t = 0; t < 16; ++t) {
        // entry: 12 outstanding vmem = B(t) asyncs (per-wave)
        float v1[8], v2[8];
        const bool pf = (t < 15);
        if (pf) {
            const float* xn = xp + (t + 1) * 64;
            *(float4*)&v1[0] = *(const float4*)(xn);        // +4 vm -> 16
            *(float4*)&v1[4] = *(const float4*)(xn + 4);
            *(float4*)&v2[0] = *(const float4*)(xn + 16);
            *(float4*)&v2[4] = *(const float4*)(xn + 20);
            stage_B(wh, wl, &B_lds[cur ^ 1][0], t + 1, wave, lane); // +12 -> 28
            WAITVM(16);   // oldest 12 (=B(t)) complete; t+1 loads in flight
        } else {
            WAITVM(0);    // last chunk: drain B(15)
        }
        __builtin_amdgcn_sched_barrier(0);

        const short* Ac = &A_lds[cur][0];
        const short* Bc = &B_lds[cur][0];
        #pragma unroll
        for (int kcl = 0; kcl < 2; ++kcl) {
            bf16x8 ah[4], al[4];
            #pragma unroll
            for (int mt = 0; mt < 4; ++mt) {
                ah[mt] = *(const bf16x8*)&Ac[((mt * 2 + kcl) * 2 + 0) * 512 + lane * 8];
                al[mt] = *(const bf16x8*)&Ac[((mt * 2 + kcl) * 2 + 1) * 512 + lane * 8];
            }
            #pragma unroll
            for (int j = 0; j < 3; ++j) {
                const int gb = (nt0 + j) * 4 + kcl * 2;
                const bf16x8 bh = *(const bf16x8*)&Bc[(gb + 0) * 512 + lane * 8];
                const bf16x8 bl = *(const bf16x8*)&Bc[(gb + 1) * 512 + lane * 8];
                #pragma unroll
                for (int mt = 0; mt < 4; ++mt) {
                    acc[mt][j] = __builtin_amdgcn_mfma_f32_16x16x32_bf16(ah[mt], bh, acc[mt][j], 0, 0, 0);
                    acc[mt][j] = __builtin_amdgcn_mfma_f32_16x16x32_bf16(ah[mt], bl, acc[mt][j], 0, 0, 0);
                    acc[mt][j] = __builtin_amdgcn_mfma_f32_16x16x32_bf16(al[mt], bh, acc[mt][j], 0, 0, 0);
                }
            }
        }

        if (pf) {
            // convert next-chunk A (compiler inserts vmcnt(12) for v-reg use:
            // x loads were issued BEFORE the 12 B asyncs)
            short* An = &A_lds[cur ^ 1][0];
            int4 hi, lo;
            split8(v1, hi, lo);
            *(int4*)&An[(fp * 2 + 0) * 512 + l1 * 8] = hi;
            *(int4*)&An[(fp * 2 + 1) * 512 + l1 * 8] = lo;
            split8(v2, hi, lo);
            *(int4*)&An[(fp * 2 + 0) * 512 + (l1 + 32) * 8] = hi;
            *(int4*)&An[(fp * 2 + 1) * 512 + (l1 + 32) * 8] = lo;
        }
        WAITLGKM0;                     // my ds reads+writes complete
        __builtin_amdgcn_s_barrier();  // A handoff; B(t+1) still in flight
        __builtin_amdgcn_sched_barrier(0);
        cur ^= 1;
    }

    // ---- epilogue: C/D layout col=lane&15, row=(lane>>4)*4+reg
    const int quad = lane >> 4;
    const int l15  = lane & 15;
    #pragma unroll
    for (int mt = 0; mt < 4; ++mt) {
        const int rowb = r0 + mt * 16 + quad * 4;
        #pragma unroll
        for (int j = 0; j < 3; ++j) {
            const f32x4 a = acc[mt][j];
            const int c = (nt0 + j) * 16 + l15;   // 0..191
            if (c < 128) {
                const int cc    = (c < 64) ? c : (c - 64);
                const float bias = (c < 64) ? bq[cc] : bk[cc];
                short* dsth = (c < 64) ? qfh : kfh;
                short* dstl = (c < 64) ? qfl : kfl;
                const int tile16 = rowb >> 4;
                const int kc2   = cc >> 5;
                const int quadd = (cc & 31) >> 3;
                const int e     = cc & 7;
                #pragma unroll
                for (int r = 0; r < 4; ++r) {
                    const float val = a[r] + bias;
                    const unsigned int b = __float_as_uint(val);
                    const unsigned short h = (unsigned short)(b >> 16);
                    const float res = val - __uint_as_float((unsigned int)h << 16);
                    const unsigned short l16 = (unsigned short)(__float_as_uint(res) >> 16);
                    const int laned = ((rowb + r) & 15) | (quadd << 4);
                    const size_t off = ((size_t)((tile16 * 2 + kc2) * 64 + laned)) * 8 + e;
                    dsth[off] = (short)h;
                    dstl[off] = (short)l16;
                }
            } else {
                const int cv    = c - 128;
                const int vb    = rowb >> 6;
                const int jc2   = (rowb & 63) >> 5;
                const int quadd = (rowb & 31) >> 3;
                const int gg    = jc2 * 4 + (cv >> 4);
                const int laned = (cv & 15) | (quadd << 4);
                const size_t base = ((size_t)((vb * 8 + gg) * 64 + laned)) * 8 + (rowb & 7);
                short4 pk;
                pk.x = (short)f2bf_rne(a[0]);
                pk.y = (short)f2bf_rne(a[1]);
                pk.z = (short)f2bf_rne(a[2]);
                pk.w = (short)f2bf_rne(a[3]);
                *(short4*)(vf + base) = pk;
            }
        }
    }
}

// ---------------------------------------------------------------------------
// Kernel 2: flash attention via MFMA, async staging. (R1 verbatim)
// ---------------------------------------------------------------------------
__global__ __launch_bounds__(256) void attn_kernel(
    const short* __restrict__ qfh, const short* __restrict__ qfl,
    const short* __restrict__ kfh, const short* __restrict__ kfl,
    const short* __restrict__ vf, const int* __restrict__ maskp,
    float* __restrict__ part_O, float* __restrict__ part_ml, int BT)
{
    __shared__ __align__(16) short Kh[4096], Kl[4096];
    __shared__ __align__(16) short Vt[4096];
    __shared__ __align__(16) short Pl[4][16 * 72];

    const int tile  = blockIdx.x;
    const int chunk = blockIdx.y;
    const int r0 = tile * 64;
    const int tb = r0 / T_LEN;
    const int t0 = r0 - tb * T_LEN;
    const int mask = (*maskp != 0);
    const int n_max = mask ? (t0 + 64) : T_LEN;
    const int j0 = chunk * JCH;
    if (j0 >= n_max) return;
    const int hi_j = min(j0 + JCH, n_max);
    const int njt = (hi_j - j0 + 63) >> 6;

    const int tid  = threadIdx.x;
    const int w    = tid >> 6;
    const int lane = tid & 63;
    const int quad = lane >> 4;
    const int l15  = lane & 15;
    const int rw0  = t0 + 16 * w;
    const int rowa = r0 + 16 * w + quad * 4;

    bf16x8 qh[2], ql[2];
    {
        const size_t qt = (size_t)(r0 >> 4) + w;
        #pragma unroll
        for (int kc = 0; kc < 2; ++kc) {
            qh[kc] = *(const bf16x8*)&qfh[((qt * 2 + kc) * 64 + lane) * 8];
            ql[kc] = *(const bf16x8*)&qfl[((qt * 2 + kc) * 64 + lane) * 8];
        }
    }

    f32x4 oacc[4];
    #pragma unroll
    for (int nt = 0; nt < 4; ++nt) oacc[nt] = (f32x4)(0.f);
    float m_r[4] = {-INFINITY, -INFINITY, -INFINITY, -INFINITY};
    float l_r[4] = {0.f, 0.f, 0.f, 0.f};

    for (int jt = 0; jt < njt; ++jt) {
        const int jbase = j0 + jt * 64;
        __syncthreads();
        {
            const size_t kt0 = (size_t)(tb * 128) + (jbase >> 4);
            const size_t vb  = (size_t)(tb * 32) + (jbase >> 6);
            #pragma unroll
            for (int ii = 0; ii < 6; ++ii) {
                const int g = w * 6 + ii;       // 0..23
                if (g < 8) {
                    const short* src = kfh + ((kt0 + (g >> 1)) * 2 + (g & 1)) * 512;
                    async_copy16(src + lane * 8, &Kh[g * 512]);
                } else if (g < 16) {
                    const int gg = g - 8;
                    const short* src = kfl + ((kt0 + (gg >> 1)) * 2 + (gg & 1)) * 512;
                    async_copy16(src + lane * 8, &Kl[gg * 512]);
                } else {
                    const int gg = g - 16;
                    const short* src = vf + (vb * 8 + gg) * 512;
                    async_copy16(src + lane * 8, &Vt[gg * 512]);
                }
            }
        }
        __syncthreads();

        const bool active = (!mask) || (jbase <= rw0 + 15);
        if (active) {
            f32x4 sacc[4];
            #pragma unroll
            for (int jsub = 0; jsub < 4; ++jsub) {
                f32x4 s = (f32x4)(0.f);
                #pragma unroll
                for (int kc = 0; kc < 2; ++kc) {
                    const bf16x8 kh = *(const bf16x8*)&Kh[((jsub * 2 + kc) * 64 + lane) * 8];
                    const bf16x8 kl = *(const bf16x8*)&Kl[((jsub * 2 + kc) * 64 + lane) * 8];
                    s = __builtin_amdgcn_mfma_f32_16x16x32_bf16(qh[kc], kh, s, 0, 0, 0);
                    s = __builtin_amdgcn_mfma_f32_16x16x32_bf16(qh[kc], kl, s, 0, 0, 0);
                    s = __builtin_amdgcn_mfma_f32_16x16x32_bf16(ql[kc], kh, s, 0, 0, 0);
                }
                sacc[jsub] = s;
            }
            float sval[4][4], rmax[4];
            #pragma unroll
            for (int r = 0; r < 4; ++r) rmax[r] = -INFINITY;
            #pragma unroll
            for (int jsub = 0; jsub < 4; ++jsub) {
                const int jg = jbase + jsub * 16 + l15;
                #pragma unroll
                for (int r = 0; r < 4; ++r) {
                    const int tg = rw0 + quad * 4 + r;
                    const float vv = (mask && (jg > tg)) ? -INFINITY : 8.0f * sacc[jsub][r];
                    sval[jsub][r] = vv;
                    rmax[r] = fmaxf(rmax[r], vv);
                }
            }
            #pragma unroll
            for (int d = 1; d < 16; d <<= 1)
                #pragma unroll
                for (int r = 0; r < 4; ++r)
                    rmax[r] = fmaxf(rmax[r], __shfl_xor(rmax[r], d));
            float alpha[4], msafe[4];
            #pragma unroll
            for (int r = 0; r < 4; ++r) {
                const float mn = fmaxf(m_r[r], rmax[r]);
                msafe[r] = (mn == -INFINITY) ? 0.f : mn;
                alpha[r] = __expf(m_r[r] - msafe[r]);
                m_r[r] = mn;
            }
            short* Pw = &Pl[w][0];
            float rsum[4] = {0.f, 0.f, 0.f, 0.f};
            #pragma unroll
            for (int jsub = 0; jsub < 4; ++jsub) {
                #pragma unroll
                for (int r = 0; r < 4; ++r) {
                    const float e = __expf(sval[jsub][r] - msafe[r]);
                    const unsigned short eb = f2bf_rne(e);
                    Pw[(quad * 4 + r) * 72 + jsub * 16 + l15] = (short)eb;
                    rsum[r] += bf2f(eb);
                }
            }
            #pragma unroll
            for (int d = 1; d < 16; d <<= 1)
                #pragma unroll
                for (int r = 0; r < 4; ++r)
                    rsum[r] += __shfl_xor(rsum[r], d);
            #pragma unroll
            for (int r = 0; r < 4; ++r)
                l_r[r] = l_r[r] * alpha[r] + rsum[r];
            #pragma unroll
            for (int nt = 0; nt < 4; ++nt)
                #pragma unroll
                for (int r = 0; r < 4; ++r)
                    oacc[nt][r] *= alpha[r];
            bf16x8 pf[2];
            #pragma unroll
            for (int jc = 0; jc < 2; ++jc)
                pf[jc] = *(const bf16x8*)&Pw[l15 * 72 + jc * 32 + quad * 8];
            #pragma unroll
            for (int nt = 0; nt < 4; ++nt) {
                #pragma unroll
                for (int jc = 0; jc < 2; ++jc) {
                    const bf16x8 vfr = *(const bf16x8*)&Vt[((jc * 4 + nt) * 64 + lane) * 8];
                    oacc[nt] = __builtin_amdgcn_mfma_f32_16x16x32_bf16(pf[jc], vfr, oacc[nt], 0, 0, 0);
                }
            }
        }
    }

    #pragma unroll
    for (int nt = 0; nt < 4; ++nt)
        #pragma unroll
        for (int r = 0; r < 4; ++r)
            part_O[((size_t)(rowa + r) * NCH + chunk) * HS + nt * 16 + l15] = oacc[nt][r];
    if (l15 == 0) {
        #pragma unroll
        for (int r = 0; r < 4; ++r) {
            float2 ml;
            ml.x = m_r[r];
            ml.y = l_r[r];
            *(float2*)(part_ml + ((size_t)(rowa + r) * NCH + chunk) * 2) = ml;
        }
    }
}

// ---------------------------------------------------------------------------
// Kernel 3: combine chunk partials — vectorized. (R1 verbatim)
// ---------------------------------------------------------------------------
__global__ __launch_bounds__(256) void combine_kernel(
    const float* __restrict__ part_O, const float* __restrict__ part_ml,
    const int* __restrict__ maskp, float* __restrict__ out)
{
    const int f = blockIdx.x * 256 + threadIdx.x;   // BT*16 threads total
    const int row = f >> 4;
    const int d4 = (f & 15) * 4;
    const int t = row & (T_LEN - 1);
    const int mask = (*maskp != 0);
    const int n = mask ? (t + 1) : T_LEN;
    const int nc = (n + JCH - 1) / JCH;

    const float2* mlp = (const float2*)(part_ml + (size_t)row * NCH * 2);
    float M = -INFINITY;
    for (int c = 0; c < nc; ++c) M = fmaxf(M, mlp[c].x);
    float L = 0.f;
    float Ox = 0.f, Oy = 0.f, Oz = 0.f, Ow = 0.f;
    for (int c = 0; c < nc; ++c) {
        const float2 ml = mlp[c];
        const float w = __expf(ml.x - M);
        L += ml.y * w;
        const float4 p = *(const float4*)(part_O + ((size_t)row * NCH + c) * HS + d4);
        Ox = fmaf(p.x, w, Ox);
        Oy = fmaf(p.y, w, Oy);
        Oz = fmaf(p.z, w, Oz);
        Ow = fmaf(p.w, w, Ow);
    }
    float4 res;
    res.x = Ox / L;
    res.y = Oy / L;
    res.z = Oz / L;
    res.w = Ow / L;
    *(float4*)(out + (size_t)row * HS + d4) = res;
}

// ---------------------------------------------------------------------------
extern "C" void kernel_launch(void* const* d_in, const int* in_sizes, int n_in,
                              void* d_out, int out_size, void* d_ws, size_t ws_size,
                              hipStream_t stream) {
    const float* x  = (const float*)d_in[0];
    const float* Wq = (const float*)d_in[1];
    const float* bq = (const float*)d_in[2];
    const float* Wk = (const float*)d_in[3];
    const float* bk = (const float*)d_in[4];
    const float* Wv = (const float*)d_in[5];
    const int* maskp = (const int*)d_in[6];

    const int BT = in_sizes[0] / D_MODEL;   // 8192

    // ws layout: floats pO [BT*NCH*64], pml [BT*NCH*2]; shorts wh,wl
    // [192*1024], qfh,qfl,kfh,kfl,vf [BT*64].
    float* pO  = (float*)d_ws;
    float* pml = pO + (size_t)BT * NCH * HS;
    short* wh  = (short*)(pml + (size_t)BT * NCH * 2);
    short* wl  = wh + (size_t)192 * D_MODEL;
    short* qfh = wl + (size_t)192 * D_MODEL;
    short* qfl = qfh + (size_t)BT * HS;
    short* kfh = qfl + (size_t)BT * HS;
    short* kfl = kfh + (size_t)BT * HS;
    short* vf  = kfl + (size_t)BT * HS;

    prep_kernel<<<48, 256, 0, stream>>>(Wq, Wk, Wv, wh, wl);
    qkv_kernel<<<BT / 64, 256, 0, stream>>>(x, wh, wl, bq, bk,
                                            qfh, qfl, kfh, kfl, vf);
    dim3 agrid(BT / 64, NCH);
    attn_kernel<<<agrid, 256, 0, stream>>>(qfh, qfl, kfh, kfl, vf, maskp,
                                           pO, pml, BT);
    combine_kernel<<<(BT * 16) / 256, 256, 0, stream>>>(pO, pml, maskp, (float*)d_out);
}

// Round 6
// 142.869 us; speedup vs baseline: 1.8211x; 1.0340x over previous
//
#include <hip/hip_runtime.h>
#include <hip/hip_bf16.h>

// AttentionHead: B=4, T=2048, C=1024, hs=64. All fp32 in/out.
// Round 6: qkv rewritten BARRIER-FREE and LDS-FREE — each wave loads A (x)
// directly in MFMA fragment layout + converts in-register; B (pre-split W)
// loaded straight from L2 into registers. 512-thread blocks, 8 waves
// (mt = w&1, nt0 = 3*(w>>1)), grid BT/32 = 256, 2 waves/SIMD.
// prep/attn/combine unchanged (proven).
#define D_MODEL 1024
#define HS 64
#define T_LEN 2048
#define JCH 256          // j-chunk width per attention block
#define NCH 8            // max chunks per row = T_LEN/JCH

typedef __attribute__((ext_vector_type(8))) short bf16x8;   // MFMA A/B frag
typedef __attribute__((ext_vector_type(4))) float f32x4;    // MFMA C/D frag

// split 8 floats into hi/lo bf16 (truncation split: residual exact)
__device__ inline void split8(const float* v, int4& hi, int4& lo) {
    union { unsigned short u[8]; int4 v4; } uh, ul;
    #pragma unroll
    for (int i = 0; i < 8; ++i) {
        const unsigned int b = __float_as_uint(v[i]);
        const unsigned short h = (unsigned short)(b >> 16);
        const float r = v[i] - __uint_as_float((unsigned int)h << 16);
        uh.u[i] = h;
        ul.u[i] = (unsigned short)(__float_as_uint(r) >> 16);
    }
    hi = uh.v4; lo = ul.v4;
}

// same split but straight into MFMA register fragments
__device__ inline void split8b(const float* v, bf16x8& hi, bf16x8& lo) {
    union { unsigned short u[8]; bf16x8 v8; } uh, ul;
    #pragma unroll
    for (int i = 0; i < 8; ++i) {
        const unsigned int b = __float_as_uint(v[i]);
        const unsigned short h = (unsigned short)(b >> 16);
        const float r = v[i] - __uint_as_float((unsigned int)h << 16);
        uh.u[i] = h;
        ul.u[i] = (unsigned short)(__float_as_uint(r) >> 16);
    }
    hi = uh.v8; lo = ul.v8;
}

// fp32 -> bf16 round-to-nearest-even (finite inputs only here)
__device__ inline unsigned short f2bf_rne(float f) {
    const unsigned int b = __float_as_uint(f);
    return (unsigned short)((b + 0x7FFFu + ((b >> 16) & 1u)) >> 16);
}
__device__ inline float bf2f(unsigned short h) {
    return __uint_as_float((unsigned int)h << 16);
}

// async 16B global -> LDS (direct-to-shared DMA). LDS dest is wave-uniform
// base; HW writes ldsbase + lane*16. gptr is per-lane.
__device__ inline void async_copy16(const short* g, short* l) {
    __builtin_amdgcn_global_load_lds(
        (const __attribute__((address_space(1))) void*)g,
        (__attribute__((address_space(3))) void*)l, 16, 0, 0);
}

// ---------------------------------------------------------------------------
// Kernel 0: prep — W ONLY. Grid: 48 blocks = 3 matrices x 16 k-blocks.
// Output wh/wl layout: ((g_nt*32 + kc)*64 + lane)*8, g_nt = m*4+ntl in 0..11.
// ---------------------------------------------------------------------------
__global__ __launch_bounds__(256) void prep_kernel(
    const float* __restrict__ Wq, const float* __restrict__ Wk,
    const float* __restrict__ Wv,
    short* __restrict__ wh, short* __restrict__ wl)
{
    __shared__ float tile[64][69];
    const int tid = threadIdx.x;
    const int wb  = blockIdx.x;
    const int kb  = wb & 15;           // k-block 0..15
    const int m   = wb >> 4;           // matrix 0..2
    const float* W = (m == 0) ? Wq : (m == 1) ? Wk : Wv;
    #pragma unroll
    for (int it = 0; it < 4; ++it) {
        const int idx = tid + 256 * it;
        const int kr = idx >> 4, c4 = idx & 15;
        *(float4*)&tile[kr][4 * c4] =
            *(const float4*)(W + (size_t)(kb * 64 + kr) * HS + 4 * c4);
    }
    __syncthreads();
    #pragma unroll
    for (int i = 0; i < 2; ++i) {
        const int s    = tid + 256 * i;    // 0..511
        const int ntl  = s >> 7;
        const int kcl  = (s >> 6) & 1;
        const int lane = s & 63;
        const int n    = ntl * 16 + (lane & 15);
        const int krel = kcl * 32 + (lane >> 4) * 8;
        float v[8];
        #pragma unroll
        for (int e = 0; e < 8; ++e) v[e] = tile[krel + e][n];
        int4 hi, lo;
        split8(v, hi, lo);
        const size_t off =
            ((size_t)((m * 4 + ntl) * 32 + kb * 2 + kcl) * 64 + lane) * 8;
        *(int4*)(wh + off) = hi;
        *(int4*)(wl + off) = lo;
    }
}

// ---------------------------------------------------------------------------
// Kernel 1: QKV projection — barrier-free, LDS-free, all-register.
// Grid: BT/32 = 256 blocks x 512 threads (8 waves, 2/SIMD w/ launch_bounds).
// Wave w: rows [r0 + (w&1)*16, +16), output n-tiles 3*(w>>1)..+2.
// Per 64-k chunk: load x-fragment (4x float4, in MFMA A layout), load 12 B
// frags (bf16x8 from L2-resident pre-split W), split x in-register, 18 MFMA.
// Full unroll -> compiler software-pipelines loads across chunks; no sync.
// ---------------------------------------------------------------------------
__global__ __launch_bounds__(512, 2) void qkv_kernel(
    const float* __restrict__ x,
    const short* __restrict__ wh, const short* __restrict__ wl,
    const float* __restrict__ bq, const float* __restrict__ bk,
    short* __restrict__ qfh, short* __restrict__ qfl,
    short* __restrict__ kfh, short* __restrict__ kfl, short* __restrict__ vf)
{
    const int tid  = threadIdx.x;
    const int wv   = tid >> 6;          // 0..7
    const int lane = tid & 63;
    const int mt   = wv & 1;            // row sub-tile
    const int nt0  = (wv >> 1) * 3;     // first output n-tile
    const int r0   = blockIdx.x * 32;

    // A-fragment source: row = r0 + mt*16 + (lane&15), k ofs = (lane>>4)*8
    const float* xrow = x + (size_t)(r0 + mt * 16 + (lane & 15)) * D_MODEL
                          + (lane >> 4) * 8;

    f32x4 acc[3];
    #pragma unroll
    for (int j = 0; j < 3; ++j) acc[j] = (f32x4)(0.f);

    #pragma unroll
    for (int t = 0; t < 16; ++t) {
        const float* xc = xrow + t * 64;
        float v0[8], v1[8];
        *(float4*)&v0[0] = *(const float4*)(xc);
        *(float4*)&v0[4] = *(const float4*)(xc + 4);
        *(float4*)&v1[0] = *(const float4*)(xc + 32);
        *(float4*)&v1[4] = *(const float4*)(xc + 36);

        bf16x8 bh[2][3], bl[2][3];
        #pragma unroll
        for (int kcl = 0; kcl < 2; ++kcl)
            #pragma unroll
            for (int j = 0; j < 3; ++j) {
                const size_t off =
                    ((size_t)((nt0 + j) * 32 + t * 2 + kcl)) * 512 + lane * 8;
                bh[kcl][j] = *(const bf16x8*)&wh[off];
                bl[kcl][j] = *(const bf16x8*)&wl[off];
            }

        bf16x8 a0h, a0l, a1h, a1l;
        split8b(v0, a0h, a0l);
        split8b(v1, a1h, a1l);

        #pragma unroll
        for (int j = 0; j < 3; ++j) {
            acc[j] = __builtin_amdgcn_mfma_f32_16x16x32_bf16(a0h, bh[0][j], acc[j], 0, 0, 0);
            acc[j] = __builtin_amdgcn_mfma_f32_16x16x32_bf16(a0h, bl[0][j], acc[j], 0, 0, 0);
            acc[j] = __builtin_amdgcn_mfma_f32_16x16x32_bf16(a0l, bh[0][j], acc[j], 0, 0, 0);
        }
        #pragma unroll
        for (int j = 0; j < 3; ++j) {
            acc[j] = __builtin_amdgcn_mfma_f32_16x16x32_bf16(a1h, bh[1][j], acc[j], 0, 0, 0);
            acc[j] = __builtin_amdgcn_mfma_f32_16x16x32_bf16(a1h, bl[1][j], acc[j], 0, 0, 0);
            acc[j] = __builtin_amdgcn_mfma_f32_16x16x32_bf16(a1l, bh[1][j], acc[j], 0, 0, 0);
        }
    }

    // ---- epilogue: C/D layout col=lane&15, row=(lane>>4)*4+reg
    const int quad = lane >> 4;
    const int l15  = lane & 15;
    const int rowb = r0 + mt * 16 + quad * 4;
    #pragma unroll
    for (int j = 0; j < 3; ++j) {
        const f32x4 a = acc[j];
        const int c = (nt0 + j) * 16 + l15;   // 0..191; q<64, k<128, else v
        if (c < 128) {
            const int cc    = (c < 64) ? c : (c - 64);
            const float bias = (c < 64) ? bq[cc] : bk[cc];
            short* dsth = (c < 64) ? qfh : kfh;
            short* dstl = (c < 64) ? qfl : kfl;
            const int tile16 = rowb >> 4;
            const int kc2   = cc >> 5;
            const int quadd = (cc & 31) >> 3;
            const int e     = cc & 7;
            #pragma unroll
            for (int r = 0; r < 4; ++r) {
                const float val = a[r] + bias;
                const unsigned int b = __float_as_uint(val);
                const unsigned short h = (unsigned short)(b >> 16);
                const float res = val - __uint_as_float((unsigned int)h << 16);
                const unsigned short l16 = (unsigned short)(__float_as_uint(res) >> 16);
                const int laned = ((rowb + r) & 15) | (quadd << 4);
                const size_t off = ((size_t)((tile16 * 2 + kc2) * 64 + laned)) * 8 + e;
                dsth[off] = (short)h;
                dstl[off] = (short)l16;
            }
        } else {
            const int cv    = c - 128;
            const int vb    = rowb >> 6;
            const int jc2   = (rowb & 63) >> 5;
            const int quadd = (rowb & 31) >> 3;
            const int gg    = jc2 * 4 + (cv >> 4);
            const int laned = (cv & 15) | (quadd << 4);
            const size_t base = ((size_t)((vb * 8 + gg) * 64 + laned)) * 8 + (rowb & 7);
            short4 pk;
            pk.x = (short)f2bf_rne(a[0]);
            pk.y = (short)f2bf_rne(a[1]);
            pk.z = (short)f2bf_rne(a[2]);
            pk.w = (short)f2bf_rne(a[3]);
            *(short4*)(vf + base) = pk;
        }
    }
}

// ---------------------------------------------------------------------------
// Kernel 2: flash attention via MFMA, async staging. (unchanged, proven)
// ---------------------------------------------------------------------------
__global__ __launch_bounds__(256) void attn_kernel(
    const short* __restrict__ qfh, const short* __restrict__ qfl,
    const short* __restrict__ kfh, const short* __restrict__ kfl,
    const short* __restrict__ vf, const int* __restrict__ maskp,
    float* __restrict__ part_O, float* __restrict__ part_ml, int BT)
{
    __shared__ __align__(16) short Kh[4096], Kl[4096];
    __shared__ __align__(16) short Vt[4096];
    __shared__ __align__(16) short Pl[4][16 * 72];

    const int tile  = blockIdx.x;
    const int chunk = blockIdx.y;
    const int r0 = tile * 64;
    const int tb = r0 / T_LEN;
    const int t0 = r0 - tb * T_LEN;
    const int mask = (*maskp != 0);
    const int n_max = mask ? (t0 + 64) : T_LEN;
    const int j0 = chunk * JCH;
    if (j0 >= n_max) return;
    const int hi_j = min(j0 + JCH, n_max);
    const int njt = (hi_j - j0 + 63) >> 6;

    const int tid  = threadIdx.x;
    const int w    = tid >> 6;
    const int lane = tid & 63;
    const int quad = lane >> 4;
    const int l15  = lane & 15;
    const int rw0  = t0 + 16 * w;
    const int rowa = r0 + 16 * w + quad * 4;

    bf16x8 qh[2], ql[2];
    {
        const size_t qt = (size_t)(r0 >> 4) + w;
        #pragma unroll
        for (int kc = 0; kc < 2; ++kc) {
            qh[kc] = *(const bf16x8*)&qfh[((qt * 2 + kc) * 64 + lane) * 8];
            ql[kc] = *(const bf16x8*)&qfl[((qt * 2 + kc) * 64 + lane) * 8];
        }
    }

    f32x4 oacc[4];
    #pragma unroll
    for (int nt = 0; nt < 4; ++nt) oacc[nt] = (f32x4)(0.f);
    float m_r[4] = {-INFINITY, -INFINITY, -INFINITY, -INFINITY};
    float l_r[4] = {0.f, 0.f, 0.f, 0.f};

    for (int jt = 0; jt < njt; ++jt) {
        const int jbase = j0 + jt * 64;
        __syncthreads();
        {
            const size_t kt0 = (size_t)(tb * 128) + (jbase >> 4);
            const size_t vb  = (size_t)(tb * 32) + (jbase >> 6);
            #pragma unroll
            for (int ii = 0; ii < 6; ++ii) {
                const int g = w * 6 + ii;       // 0..23
                if (g < 8) {
                    const short* src = kfh + ((kt0 + (g >> 1)) * 2 + (g & 1)) * 512;
                    async_copy16(src + lane * 8, &Kh[g * 512]);
                } else if (g < 16) {
                    const int gg = g - 8;
                    const short* src = kfl + ((kt0 + (gg >> 1)) * 2 + (gg & 1)) * 512;
                    async_copy16(src + lane * 8, &Kl[gg * 512]);
                } else {
                    const int gg = g - 16;
                    const short* src = vf + (vb * 8 + gg) * 512;
                    async_copy16(src + lane * 8, &Vt[gg * 512]);
                }
            }
        }
        __syncthreads();

        const bool active = (!mask) || (jbase <= rw0 + 15);
        if (active) {
            f32x4 sacc[4];
            #pragma unroll
            for (int jsub = 0; jsub < 4; ++jsub) {
                f32x4 s = (f32x4)(0.f);
                #pragma unroll
                for (int kc = 0; kc < 2; ++kc) {
                    const bf16x8 kh = *(const bf16x8*)&Kh[((jsub * 2 + kc) * 64 + lane) * 8];
                    const bf16x8 kl = *(const bf16x8*)&Kl[((jsub * 2 + kc) * 64 + lane) * 8];
                    s = __builtin_amdgcn_mfma_f32_16x16x32_bf16(qh[kc], kh, s, 0, 0, 0);
                    s = __builtin_amdgcn_mfma_f32_16x16x32_bf16(qh[kc], kl, s, 0, 0, 0);
                    s = __builtin_amdgcn_mfma_f32_16x16x32_bf16(ql[kc], kh, s, 0, 0, 0);
                }
                sacc[jsub] = s;
            }
            float sval[4][4], rmax[4];
            #pragma unroll
            for (int r = 0; r < 4; ++r) rmax[r] = -INFINITY;
            #pragma unroll
            for (int jsub = 0; jsub < 4; ++jsub) {
                const int jg = jbase + jsub * 16 + l15;
                #pragma unroll
                for (int r = 0; r < 4; ++r) {
                    const int tg = rw0 + quad * 4 + r;
                    const float vv = (mask && (jg > tg)) ? -INFINITY : 8.0f * sacc[jsub][r];
                    sval[jsub][r] = vv;
                    rmax[r] = fmaxf(rmax[r], vv);
                }
            }
            #pragma unroll
            for (int d = 1; d < 16; d <<= 1)
                #pragma unroll
                for (int r = 0; r < 4; ++r)
                    rmax[r] = fmaxf(rmax[r], __shfl_xor(rmax[r], d));
            float alpha[4], msafe[4];
            #pragma unroll
            for (int r = 0; r < 4; ++r) {
                const float mn = fmaxf(m_r[r], rmax[r]);
                msafe[r] = (mn == -INFINITY) ? 0.f : mn;
                alpha[r] = __expf(m_r[r] - msafe[r]);
                m_r[r] = mn;
            }
            short* Pw = &Pl[w][0];
            float rsum[4] = {0.f, 0.f, 0.f, 0.f};
            #pragma unroll
            for (int jsub = 0; jsub < 4; ++jsub) {
                #pragma unroll
                for (int r = 0; r < 4; ++r) {
                    const float e = __expf(sval[jsub][r] - msafe[r]);
                    const unsigned short eb = f2bf_rne(e);
                    Pw[(quad * 4 + r) * 72 + jsub * 16 + l15] = (short)eb;
                    rsum[r] += bf2f(eb);
                }
            }
            #pragma unroll
            for (int d = 1; d < 16; d <<= 1)
                #pragma unroll
                for (int r = 0; r < 4; ++r)
                    rsum[r] += __shfl_xor(rsum[r], d);
            #pragma unroll
            for (int r = 0; r < 4; ++r)
                l_r[r] = l_r[r] * alpha[r] + rsum[r];
            #pragma unroll
            for (int nt = 0; nt < 4; ++nt)
                #pragma unroll
                for (int r = 0; r < 4; ++r)
                    oacc[nt][r] *= alpha[r];
            bf16x8 pf[2];
            #pragma unroll
            for (int jc = 0; jc < 2; ++jc)
                pf[jc] = *(const bf16x8*)&Pw[l15 * 72 + jc * 32 + quad * 8];
            #pragma unroll
            for (int nt = 0; nt < 4; ++nt) {
                #pragma unroll
                for (int jc = 0; jc < 2; ++jc) {
                    const bf16x8 vfr = *(const bf16x8*)&Vt[((jc * 4 + nt) * 64 + lane) * 8];
                    oacc[nt] = __builtin_amdgcn_mfma_f32_16x16x32_bf16(pf[jc], vfr, oacc[nt], 0, 0, 0);
                }
            }
        }
    }

    #pragma unroll
    for (int nt = 0; nt < 4; ++nt)
        #pragma unroll
        for (int r = 0; r < 4; ++r)
            part_O[((size_t)(rowa + r) * NCH + chunk) * HS + nt * 16 + l15] = oacc[nt][r];
    if (l15 == 0) {
        #pragma unroll
        for (int r = 0; r < 4; ++r) {
            float2 ml;
            ml.x = m_r[r];
            ml.y = l_r[r];
            *(float2*)(part_ml + ((size_t)(rowa + r) * NCH + chunk) * 2) = ml;
        }
    }
}

// ---------------------------------------------------------------------------
// Kernel 3: combine chunk partials — vectorized. (unchanged)
// ---------------------------------------------------------------------------
__global__ __launch_bounds__(256) void combine_kernel(
    const float* __restrict__ part_O, const float* __restrict__ part_ml,
    const int* __restrict__ maskp, float* __restrict__ out)
{
    const int f = blockIdx.x * 256 + threadIdx.x;   // BT*16 threads total
    const int row = f >> 4;
    const int d4 = (f & 15) * 4;
    const int t = row & (T_LEN - 1);
    const int mask = (*maskp != 0);
    const int n = mask ? (t + 1) : T_LEN;
    const int nc = (n + JCH - 1) / JCH;

    const float2* mlp = (const float2*)(part_ml + (size_t)row * NCH * 2);
    float M = -INFINITY;
    for (int c = 0; c < nc; ++c) M = fmaxf(M, mlp[c].x);
    float L = 0.f;
    float Ox = 0.f, Oy = 0.f, Oz = 0.f, Ow = 0.f;
    for (int c = 0; c < nc; ++c) {
        const float2 ml = mlp[c];
        const float w = __expf(ml.x - M);
        L += ml.y * w;
        const float4 p = *(const float4*)(part_O + ((size_t)row * NCH + c) * HS + d4);
        Ox = fmaf(p.x, w, Ox);
        Oy = fmaf(p.y, w, Oy);
        Oz = fmaf(p.z, w, Oz);
        Ow = fmaf(p.w, w, Ow);
    }
    float4 res;
    res.x = Ox / L;
    res.y = Oy / L;
    res.z = Oz / L;
    res.w = Ow / L;
    *(float4*)(out + (size_t)row * HS + d4) = res;
}

// ---------------------------------------------------------------------------
extern "C" void kernel_launch(void* const* d_in, const int* in_sizes, int n_in,
                              void* d_out, int out_size, void* d_ws, size_t ws_size,
                              hipStream_t stream) {
    const float* x  = (const float*)d_in[0];
    const float* Wq = (const float*)d_in[1];
    const float* bq = (const float*)d_in[2];
    const float* Wk = (const float*)d_in[3];
    const float* bk = (const float*)d_in[4];
    const float* Wv = (const float*)d_in[5];
    const int* maskp = (const int*)d_in[6];

    const int BT = in_sizes[0] / D_MODEL;   // 8192

    // ws layout: floats pO [BT*NCH*64], pml [BT*NCH*2]; shorts wh,wl
    // [192*1024], qfh,qfl,kfh,kfl,vf [BT*64].
    float* pO  = (float*)d_ws;
    float* pml = pO + (size_t)BT * NCH * HS;
    short* wh  = (short*)(pml + (size_t)BT * NCH * 2);
    short* wl  = wh + (size_t)192 * D_MODEL;
    short* qfh = wl + (size_t)192 * D_MODEL;
    short* qfl = qfh + (size_t)BT * HS;
    short* kfh = qfl + (size_t)BT * HS;
    short* kfl = kfh + (size_t)BT * HS;
    short* vf  = kfl + (size_t)BT * HS;

    prep_kernel<<<48, 256, 0, stream>>>(Wq, Wk, Wv, wh, wl);
    qkv_kernel<<<BT / 32, 512, 0, stream>>>(x, wh, wl, bq, bk,
                                            qfh, qfl, kfh, kfl, vf);
    dim3 agrid(BT / 64, NCH);
    attn_kernel<<<agrid, 256, 0, stream>>>(qfh, qfl, kfh, kfl, vf, maskp,
                                           pO, pml, BT);
    combine_kernel<<<(BT * 16) / 256, 256, 0, stream>>>(pO, pml, maskp, (float*)d_out);
}

// Round 7
// 141.315 us; speedup vs baseline: 1.8411x; 1.0110x over previous
//
#include <hip/hip_runtime.h>
#include <hip/hip_bf16.h>

// AttentionHead: B=4, T=2048, C=1024, hs=64. All fp32 in/out.
// Round 7: qkv = barrier-free all-register GEMM with EXPLICIT 2-deep
// register-bank pipeline (R6's version compiled to VGPR=32 -> fully
// serialized loads, 6600cy/chunk). Named banks force the allocator to
// hold next-chunk loads in flight while computing the current chunk.
// prep/attn/combine unchanged (proven).
#define D_MODEL 1024
#define HS 64
#define T_LEN 2048
#define JCH 256          // j-chunk width per attention block
#define NCH 8            // max chunks per row = T_LEN/JCH

typedef __attribute__((ext_vector_type(8))) short bf16x8;   // MFMA A/B frag
typedef __attribute__((ext_vector_type(4))) float f32x4;    // MFMA C/D frag

// split 8 floats into hi/lo bf16 (truncation split: residual exact)
__device__ inline void split8(const float* v, int4& hi, int4& lo) {
    union { unsigned short u[8]; int4 v4; } uh, ul;
    #pragma unroll
    for (int i = 0; i < 8; ++i) {
        const unsigned int b = __float_as_uint(v[i]);
        const unsigned short h = (unsigned short)(b >> 16);
        const float r = v[i] - __uint_as_float((unsigned int)h << 16);
        uh.u[i] = h;
        ul.u[i] = (unsigned short)(__float_as_uint(r) >> 16);
    }
    hi = uh.v4; lo = ul.v4;
}

// fp32 -> bf16 round-to-nearest-even (finite inputs only here)
__device__ inline unsigned short f2bf_rne(float f) {
    const unsigned int b = __float_as_uint(f);
    return (unsigned short)((b + 0x7FFFu + ((b >> 16) & 1u)) >> 16);
}
__device__ inline float bf2f(unsigned short h) {
    return __uint_as_float((unsigned int)h << 16);
}

// async 16B global -> LDS (direct-to-shared DMA). LDS dest is wave-uniform
// base; HW writes ldsbase + lane*16. gptr is per-lane.
__device__ inline void async_copy16(const short* g, short* l) {
    __builtin_amdgcn_global_load_lds(
        (const __attribute__((address_space(1))) void*)g,
        (__attribute__((address_space(3))) void*)l, 16, 0, 0);
}

// ---------------------------------------------------------------------------
// Kernel 0: prep — W ONLY. Grid: 48 blocks = 3 matrices x 16 k-blocks.
// Output wh/wl layout: ((g_nt*32 + kc)*64 + lane)*8, g_nt = m*4+ntl in 0..11.
// ---------------------------------------------------------------------------
__global__ __launch_bounds__(256) void prep_kernel(
    const float* __restrict__ Wq, const float* __restrict__ Wk,
    const float* __restrict__ Wv,
    short* __restrict__ wh, short* __restrict__ wl)
{
    __shared__ float tile[64][69];
    const int tid = threadIdx.x;
    const int wb  = blockIdx.x;
    const int kb  = wb & 15;           // k-block 0..15
    const int m   = wb >> 4;           // matrix 0..2
    const float* W = (m == 0) ? Wq : (m == 1) ? Wk : Wv;
    #pragma unroll
    for (int it = 0; it < 4; ++it) {
        const int idx = tid + 256 * it;
        const int kr = idx >> 4, c4 = idx & 15;
        *(float4*)&tile[kr][4 * c4] =
            *(const float4*)(W + (size_t)(kb * 64 + kr) * HS + 4 * c4);
    }
    __syncthreads();
    #pragma unroll
    for (int i = 0; i < 2; ++i) {
        const int s    = tid + 256 * i;    // 0..511
        const int ntl  = s >> 7;
        const int kcl  = (s >> 6) & 1;
        const int lane = s & 63;
        const int n    = ntl * 16 + (lane & 15);
        const int krel = kcl * 32 + (lane >> 4) * 8;
        float v[8];
        #pragma unroll
        for (int e = 0; e < 8; ++e) v[e] = tile[krel + e][n];
        int4 hi, lo;
        split8(v, hi, lo);
        const size_t off =
            ((size_t)((m * 4 + ntl) * 32 + kb * 2 + kcl) * 64 + lane) * 8;
        *(int4*)(wh + off) = hi;
        *(int4*)(wl + off) = lo;
    }
}

// ---------------------------------------------------------------------------
// qkv pipeline banks (all statically indexed; fully inlined)
// ---------------------------------------------------------------------------
struct BankX { float4 a, b, c, d; };            // x[k0..7], x[k8..15]? no:
// a=cols[0..3], b=cols[4..7] (kcl=0 frag), c=cols[32..35], d=cols[36..39]
struct BankB { bf16x8 h[6]; bf16x8 l[6]; };     // idx = kcl*3 + j

__device__ __forceinline__ void load_x(BankX& bx, const float* xc) {
    bx.a = *(const float4*)(xc);
    bx.b = *(const float4*)(xc + 4);
    bx.c = *(const float4*)(xc + 32);
    bx.d = *(const float4*)(xc + 36);
}

__device__ __forceinline__ void load_b(BankB& bb,
                                       const short* __restrict__ wh,
                                       const short* __restrict__ wl,
                                       int nt0, int t, int lane) {
    #pragma unroll
    for (int kcl = 0; kcl < 2; ++kcl)
        #pragma unroll
        for (int j = 0; j < 3; ++j) {
            const size_t off =
                ((size_t)((nt0 + j) * 32 + t * 2 + kcl)) * 512 + lane * 8;
            bb.h[kcl * 3 + j] = *(const bf16x8*)&wh[off];
            bb.l[kcl * 3 + j] = *(const bf16x8*)&wl[off];
        }
}

// split two float4 (8 consecutive k) into hi/lo bf16 frags, no union
__device__ __forceinline__ void split_frag(const float4& p, const float4& q,
                                           bf16x8& hi, bf16x8& lo) {
    const float v[8] = {p.x, p.y, p.z, p.w, q.x, q.y, q.z, q.w};
    #pragma unroll
    for (int i = 0; i < 8; ++i) {
        const unsigned int b = __float_as_uint(v[i]);
        const unsigned short h = (unsigned short)(b >> 16);
        const float r = v[i] - __uint_as_float((unsigned int)h << 16);
        hi[i] = (short)h;
        lo[i] = (short)(__float_as_uint(r) >> 16);
    }
}

__device__ __forceinline__ void compute_chunk(f32x4 acc[3],
                                              const BankX& bx, const BankB& bb) {
    bf16x8 a0h, a0l, a1h, a1l;
    split_frag(bx.a, bx.b, a0h, a0l);   // kcl = 0
    split_frag(bx.c, bx.d, a1h, a1l);   // kcl = 1
    #pragma unroll
    for (int j = 0; j < 3; ++j) {
        acc[j] = __builtin_amdgcn_mfma_f32_16x16x32_bf16(a0h, bb.h[j], acc[j], 0, 0, 0);
        acc[j] = __builtin_amdgcn_mfma_f32_16x16x32_bf16(a0h, bb.l[j], acc[j], 0, 0, 0);
        acc[j] = __builtin_amdgcn_mfma_f32_16x16x32_bf16(a0l, bb.h[j], acc[j], 0, 0, 0);
    }
    #pragma unroll
    for (int j = 0; j < 3; ++j) {
        acc[j] = __builtin_amdgcn_mfma_f32_16x16x32_bf16(a1h, bb.h[3 + j], acc[j], 0, 0, 0);
        acc[j] = __builtin_amdgcn_mfma_f32_16x16x32_bf16(a1h, bb.l[3 + j], acc[j], 0, 0, 0);
        acc[j] = __builtin_amdgcn_mfma_f32_16x16x32_bf16(a1l, bb.h[3 + j], acc[j], 0, 0, 0);
    }
}

// ---------------------------------------------------------------------------
// Kernel 1: QKV projection — barrier-free, LDS-free, 2-deep register pipeline.
// Grid: BT/32 = 256 blocks x 512 threads (8 waves). Wave w: rows
// [r0+(w&1)*16, +16), n-tiles 3*(w>>1)..+2. Banks alternate via manual
// 2x unroll -> all indices static, loads for t+1 in flight during compute(t).
// ---------------------------------------------------------------------------
__global__ __launch_bounds__(512, 2) void qkv_kernel(
    const float* __restrict__ x,
    const short* __restrict__ wh, const short* __restrict__ wl,
    const float* __restrict__ bq, const float* __restrict__ bk,
    short* __restrict__ qfh, short* __restrict__ qfl,
    short* __restrict__ kfh, short* __restrict__ kfl, short* __restrict__ vf)
{
    const int tid  = threadIdx.x;
    const int wv   = tid >> 6;          // 0..7
    const int lane = tid & 63;
    const int mt   = wv & 1;            // row sub-tile
    const int nt0  = (wv >> 1) * 3;     // first output n-tile
    const int r0   = blockIdx.x * 32;

    const float* xrow = x + (size_t)(r0 + mt * 16 + (lane & 15)) * D_MODEL
                          + (lane >> 4) * 8;

    f32x4 acc[3];
    #pragma unroll
    for (int j = 0; j < 3; ++j) acc[j] = (f32x4)(0.f);

    BankX x0, x1;
    BankB b0, b1;

    // prologue: bank0 <- chunk 0
    load_x(x0, xrow);
    load_b(b0, wh, wl, nt0, 0, lane);

    #pragma unroll
    for (int t2 = 0; t2 < 8; ++t2) {
        const int t = 2 * t2;
        // issue chunk t+1 into bank1, then compute chunk t from bank0.
        // compiler's waitcnt before compute counts only bank0's loads.
        if (t + 1 < 16) {
            load_x(x1, xrow + (t + 1) * 64);
            load_b(b1, wh, wl, nt0, t + 1, lane);
        }
        compute_chunk(acc, x0, b0);
        if (t + 2 < 16) {
            load_x(x0, xrow + (t + 2) * 64);
            load_b(b0, wh, wl, nt0, t + 2, lane);
        }
        compute_chunk(acc, x1, b1);
    }

    // ---- epilogue: C/D layout col=lane&15, row=(lane>>4)*4+reg
    const int quad = lane >> 4;
    const int l15  = lane & 15;
    const int rowb = r0 + mt * 16 + quad * 4;
    #pragma unroll
    for (int j = 0; j < 3; ++j) {
        const f32x4 a = acc[j];
        const int c = (nt0 + j) * 16 + l15;   // 0..191; q<64, k<128, else v
        if (c < 128) {
            const int cc    = (c < 64) ? c : (c - 64);
            const float bias = (c < 64) ? bq[cc] : bk[cc];
            short* dsth = (c < 64) ? qfh : kfh;
            short* dstl = (c < 64) ? qfl : kfl;
            const int tile16 = rowb >> 4;
            const int kc2   = cc >> 5;
            const int quadd = (cc & 31) >> 3;
            const int e     = cc & 7;
            #pragma unroll
            for (int r = 0; r < 4; ++r) {
                const float val = a[r] + bias;
                const unsigned int b = __float_as_uint(val);
                const unsigned short h = (unsigned short)(b >> 16);
                const float res = val - __uint_as_float((unsigned int)h << 16);
                const unsigned short l16 = (unsigned short)(__float_as_uint(res) >> 16);
                const int laned = ((rowb + r) & 15) | (quadd << 4);
                const size_t off = ((size_t)((tile16 * 2 + kc2) * 64 + laned)) * 8 + e;
                dsth[off] = (short)h;
                dstl[off] = (short)l16;
            }
        } else {
            const int cv    = c - 128;
            const int vb    = rowb >> 6;
            const int jc2   = (rowb & 63) >> 5;
            const int quadd = (rowb & 31) >> 3;
            const int gg    = jc2 * 4 + (cv >> 4);
            const int laned = (cv & 15) | (quadd << 4);
            const size_t base = ((size_t)((vb * 8 + gg) * 64 + laned)) * 8 + (rowb & 7);
            short4 pk;
            pk.x = (short)f2bf_rne(a[0]);
            pk.y = (short)f2bf_rne(a[1]);
            pk.z = (short)f2bf_rne(a[2]);
            pk.w = (short)f2bf_rne(a[3]);
            *(short4*)(vf + base) = pk;
        }
    }
}

// ---------------------------------------------------------------------------
// Kernel 2: flash attention via MFMA, async staging. (unchanged, proven)
// ---------------------------------------------------------------------------
__global__ __launch_bounds__(256) void attn_kernel(
    const short* __restrict__ qfh, const short* __restrict__ qfl,
    const short* __restrict__ kfh, const short* __restrict__ kfl,
    const short* __restrict__ vf, const int* __restrict__ maskp,
    float* __restrict__ part_O, float* __restrict__ part_ml, int BT)
{
    __shared__ __align__(16) short Kh[4096], Kl[4096];
    __shared__ __align__(16) short Vt[4096];
    __shared__ __align__(16) short Pl[4][16 * 72];

    const int tile  = blockIdx.x;
    const int chunk = blockIdx.y;
    const int r0 = tile * 64;
    const int tb = r0 / T_LEN;
    const int t0 = r0 - tb * T_LEN;
    const int mask = (*maskp != 0);
    const int n_max = mask ? (t0 + 64) : T_LEN;
    const int j0 = chunk * JCH;
    if (j0 >= n_max) return;
    const int hi_j = min(j0 + JCH, n_max);
    const int njt = (hi_j - j0 + 63) >> 6;

    const int tid  = threadIdx.x;
    const int w    = tid >> 6;
    const int lane = tid & 63;
    const int quad = lane >> 4;
    const int l15  = lane & 15;
    const int rw0  = t0 + 16 * w;
    const int rowa = r0 + 16 * w + quad * 4;

    bf16x8 qh[2], ql[2];
    {
        const size_t qt = (size_t)(r0 >> 4) + w;
        #pragma unroll
        for (int kc = 0; kc < 2; ++kc) {
            qh[kc] = *(const bf16x8*)&qfh[((qt * 2 + kc) * 64 + lane) * 8];
            ql[kc] = *(const bf16x8*)&qfl[((qt * 2 + kc) * 64 + lane) * 8];
        }
    }

    f32x4 oacc[4];
    #pragma unroll
    for (int nt = 0; nt < 4; ++nt) oacc[nt] = (f32x4)(0.f);
    float m_r[4] = {-INFINITY, -INFINITY, -INFINITY, -INFINITY};
    float l_r[4] = {0.f, 0.f, 0.f, 0.f};

    for (int jt = 0; jt < njt; ++jt) {
        const int jbase = j0 + jt * 64;
        __syncthreads();
        {
            const size_t kt0 = (size_t)(tb * 128) + (jbase >> 4);
            const size_t vb  = (size_t)(tb * 32) + (jbase >> 6);
            #pragma unroll
            for (int ii = 0; ii < 6; ++ii) {
                const int g = w * 6 + ii;       // 0..23
                if (g < 8) {
                    const short* src = kfh + ((kt0 + (g >> 1)) * 2 + (g & 1)) * 512;
                    async_copy16(src + lane * 8, &Kh[g * 512]);
                } else if (g < 16) {
                    const int gg = g - 8;
                    const short* src = kfl + ((kt0 + (gg >> 1)) * 2 + (gg & 1)) * 512;
                    async_copy16(src + lane * 8, &Kl[gg * 512]);
                } else {
                    const int gg = g - 16;
                    const short* src = vf + (vb * 8 + gg) * 512;
                    async_copy16(src + lane * 8, &Vt[gg * 512]);
                }
            }
        }
        __syncthreads();

        const bool active = (!mask) || (jbase <= rw0 + 15);
        if (active) {
            f32x4 sacc[4];
            #pragma unroll
            for (int jsub = 0; jsub < 4; ++jsub) {
                f32x4 s = (f32x4)(0.f);
                #pragma unroll
                for (int kc = 0; kc < 2; ++kc) {
                    const bf16x8 kh = *(const bf16x8*)&Kh[((jsub * 2 + kc) * 64 + lane) * 8];
                    const bf16x8 kl = *(const bf16x8*)&Kl[((jsub * 2 + kc) * 64 + lane) * 8];
                    s = __builtin_amdgcn_mfma_f32_16x16x32_bf16(qh[kc], kh, s, 0, 0, 0);
                    s = __builtin_amdgcn_mfma_f32_16x16x32_bf16(qh[kc], kl, s, 0, 0, 0);
                    s = __builtin_amdgcn_mfma_f32_16x16x32_bf16(ql[kc], kh, s, 0, 0, 0);
                }
                sacc[jsub] = s;
            }
            float sval[4][4], rmax[4];
            #pragma unroll
            for (int r = 0; r < 4; ++r) rmax[r] = -INFINITY;
            #pragma unroll
            for (int jsub = 0; jsub < 4; ++jsub) {
                const int jg = jbase + jsub * 16 + l15;
                #pragma unroll
                for (int r = 0; r < 4; ++r) {
                    const int tg = rw0 + quad * 4 + r;
                    const float vv = (mask && (jg > tg)) ? -INFINITY : 8.0f * sacc[jsub][r];
                    sval[jsub][r] = vv;
                    rmax[r] = fmaxf(rmax[r], vv);
                }
            }
            #pragma unroll
            for (int d = 1; d < 16; d <<= 1)
                #pragma unroll
                for (int r = 0; r < 4; ++r)
                    rmax[r] = fmaxf(rmax[r], __shfl_xor(rmax[r], d));
            float alpha[4], msafe[4];
            #pragma unroll
            for (int r = 0; r < 4; ++r) {
                const float mn = fmaxf(m_r[r], rmax[r]);
                msafe[r] = (mn == -INFINITY) ? 0.f : mn;
                alpha[r] = __expf(m_r[r] - msafe[r]);
                m_r[r] = mn;
            }
            short* Pw = &Pl[w][0];
            float rsum[4] = {0.f, 0.f, 0.f, 0.f};
            #pragma unroll
            for (int jsub = 0; jsub < 4; ++jsub) {
                #pragma unroll
                for (int r = 0; r < 4; ++r) {
                    const float e = __expf(sval[jsub][r] - msafe[r]);
                    const unsigned short eb = f2bf_rne(e);
                    Pw[(quad * 4 + r) * 72 + jsub * 16 + l15] = (short)eb;
                    rsum[r] += bf2f(eb);
                }
            }
            #pragma unroll
            for (int d = 1; d < 16; d <<= 1)
                #pragma unroll
                for (int r = 0; r < 4; ++r)
                    rsum[r] += __shfl_xor(rsum[r], d);
            #pragma unroll
            for (int r = 0; r < 4; ++r)
                l_r[r] = l_r[r] * alpha[r] + rsum[r];
            #pragma unroll
            for (int nt = 0; nt < 4; ++nt)
                #pragma unroll
                for (int r = 0; r < 4; ++r)
                    oacc[nt][r] *= alpha[r];
            bf16x8 pf[2];
            #pragma unroll
            for (int jc = 0; jc < 2; ++jc)
                pf[jc] = *(const bf16x8*)&Pw[l15 * 72 + jc * 32 + quad * 8];
            #pragma unroll
            for (int nt = 0; nt < 4; ++nt) {
                #pragma unroll
                for (int jc = 0; jc < 2; ++jc) {
                    const bf16x8 vfr = *(const bf16x8*)&Vt[((jc * 4 + nt) * 64 + lane) * 8];
                    oacc[nt] = __builtin_amdgcn_mfma_f32_16x16x32_bf16(pf[jc], vfr, oacc[nt], 0, 0, 0);
                }
            }
        }
    }

    #pragma unroll
    for (int nt = 0; nt < 4; ++nt)
        #pragma unroll
        for (int r = 0; r < 4; ++r)
            part_O[((size_t)(rowa + r) * NCH + chunk) * HS + nt * 16 + l15] = oacc[nt][r];
    if (l15 == 0) {
        #pragma unroll
        for (int r = 0; r < 4; ++r) {
            float2 ml;
            ml.x = m_r[r];
            ml.y = l_r[r];
            *(float2*)(part_ml + ((size_t)(rowa + r) * NCH + chunk) * 2) = ml;
        }
    }
}

// ---------------------------------------------------------------------------
// Kernel 3: combine chunk partials — vectorized. (unchanged)
// ---------------------------------------------------------------------------
__global__ __launch_bounds__(256) void combine_kernel(
    const float* __restrict__ part_O, const float* __restrict__ part_ml,
    const int* __restrict__ maskp, float* __restrict__ out)
{
    const int f = blockIdx.x * 256 + threadIdx.x;   // BT*16 threads total
    const int row = f >> 4;
    const int d4 = (f & 15) * 4;
    const int t = row & (T_LEN - 1);
    const int mask = (*maskp != 0);
    const int n = mask ? (t + 1) : T_LEN;
    const int nc = (n + JCH - 1) / JCH;

    const float2* mlp = (const float2*)(part_ml + (size_t)row * NCH * 2);
    float M = -INFINITY;
    for (int c = 0; c < nc; ++c) M = fmaxf(M, mlp[c].x);
    float L = 0.f;
    float Ox = 0.f, Oy = 0.f, Oz = 0.f, Ow = 0.f;
    for (int c = 0; c < nc; ++c) {
        const float2 ml = mlp[c];
        const float w = __expf(ml.x - M);
        L += ml.y * w;
        const float4 p = *(const float4*)(part_O + ((size_t)row * NCH + c) * HS + d4);
        Ox = fmaf(p.x, w, Ox);
        Oy = fmaf(p.y, w, Oy);
        Oz = fmaf(p.z, w, Oz);
        Ow = fmaf(p.w, w, Ow);
    }
    float4 res;
    res.x = Ox / L;
    res.y = Oy / L;
    res.z = Oz / L;
    res.w = Ow / L;
    *(float4*)(out + (size_t)row * HS + d4) = res;
}

// ---------------------------------------------------------------------------
extern "C" void kernel_launch(void* const* d_in, const int* in_sizes, int n_in,
                              void* d_out, int out_size, void* d_ws, size_t ws_size,
                              hipStream_t stream) {
    const float* x  = (const float*)d_in[0];
    const float* Wq = (const float*)d_in[1];
    const float* bq = (const float*)d_in[2];
    const float* Wk = (const float*)d_in[3];
    const float* bk = (const float*)d_in[4];
    const float* Wv = (const float*)d_in[5];
    const int* maskp = (const int*)d_in[6];

    const int BT = in_sizes[0] / D_MODEL;   // 8192

    // ws layout: floats pO [BT*NCH*64], pml [BT*NCH*2]; shorts wh,wl
    // [192*1024], qfh,qfl,kfh,kfl,vf [BT*64].
    float* pO  = (float*)d_ws;
    float* pml = pO + (size_t)BT * NCH * HS;
    short* wh  = (short*)(pml + (size_t)BT * NCH * 2);
    short* wl  = wh + (size_t)192 * D_MODEL;
    short* qfh = wl + (size_t)192 * D_MODEL;
    short* qfl = qfh + (size_t)BT * HS;
    short* kfh = qfl + (size_t)BT * HS;
    short* kfl = kfh + (size_t)BT * HS;
    short* vf  = kfl + (size_t)BT * HS;

    prep_kernel<<<48, 256, 0, stream>>>(Wq, Wk, Wv, wh, wl);
    qkv_kernel<<<BT / 32, 512, 0, stream>>>(x, wh, wl, bq, bk,
                                            qfh, qfl, kfh, kfl, vf);
    dim3 agrid(BT / 64, NCH);
    attn_kernel<<<agrid, 256, 0, stream>>>(qfh, qfl, kfh, kfl, vf, maskp,
                                           pO, pml, BT);
    combine_kernel<<<(BT * 16) / 256, 256, 0, stream>>>(pO, pml, maskp, (float*)d_out);
}